// Round 2
// baseline (142.550 us; speedup 1.0000x reference)
//
#include <hip/hip_runtime.h>

// pos/seq_lens fill for ragged batch metadata.
// d_out layout (int32): [0, num_tokens) = pos, [num_tokens, +max_num_reqs) = seq_lens.
//
// Memory-bound on the 64 MiB pos write stream. R2 changes vs R1:
//  - Lane-contiguous store layout: thread tid owns chunks of 4 tokens at
//    blockStart + g*1024 + tid*4, so every global_store_dwordx4 is a fully
//    coalesced 1 KB wave-contiguous store (R1 had 64B-strided lanes ->
//    4x cacheline transactions per store instruction).
//  - 8192 tokens/block (32/thread) -> 1 binary search per thread, then
//    monotone advance across the 8 chunks (expected ~0.5 crossings/1 KiB gap).

#define TPB 256
#define CHUNKS 8                                  // int4 chunks per thread
#define TOK_PER_BLOCK (TPB * 4 * CHUNKS)          // 8192
#define SEQ_PER_BLOCK (TPB * 4)                   // 1024

__global__ __launch_bounds__(TPB) void pos_seq_kernel(
    const int* __restrict__ idx_mapping,
    const int* __restrict__ qsl,          // [num_reqs+1]
    const int* __restrict__ nct,          // [max_num_reqs]
    int* __restrict__ pos_out,            // [num_tokens]
    int* __restrict__ seq_out,            // [max_num_reqs]
    int num_reqs, int max_num_reqs, int num_tokens,
    int pos_blocks)
{
    int b = blockIdx.x;

    if (b >= pos_blocks) {
        // ---- seq_lens part ----
        int i = (b - pos_blocks) * SEQ_PER_BLOCK + (int)threadIdx.x * 4;
        if (i >= max_num_reqs) return;
        if (i + 4 <= max_num_reqs) {
            int4 v;
            int* vp = (int*)&v;
            #pragma unroll
            for (int k = 0; k < 4; ++k) {
                int idx = i + k;
                int val = 0;
                if (idx < num_reqs)
                    val = nct[idx_mapping[idx]] + (qsl[idx + 1] - qsl[idx]);
                vp[k] = val;
            }
            *(int4*)(seq_out + i) = v;
        } else {
            for (int idx = i; idx < max_num_reqs; ++idx) {
                int val = 0;
                if (idx < num_reqs)
                    val = nct[idx_mapping[idx]] + (qsl[idx + 1] - qsl[idx]);
                seq_out[idx] = val;
            }
        }
        return;
    }

    // ---- pos part ----
    long long blockStartL = (long long)b * TOK_PER_BLOCK;
    int blockStart = (int)blockStartL;
    int tid = (int)threadIdx.x;
    int tfirst = blockStart + tid * 4;
    if (tfirst >= num_tokens) return;

    // upper_bound: last r in [0, num_reqs] with qsl[r] <= tfirst.
    // qsl[0]=0 <= t always; qsl[num_reqs]=num_tokens > t -> r <= num_reqs-1.
    int l = 0, h = num_reqs + 1;
    while (h - l > 1) {
        int mid = (l + h) >> 1;
        if (qsl[mid] <= tfirst) l = mid; else h = mid;
    }
    int r = l;
    int next = qsl[r + 1];
    int base = nct[idx_mapping[r]] - qsl[r];

    #pragma unroll
    for (int g = 0; g < CHUNKS; ++g) {
        int tc = blockStart + g * (TPB * 4) + tid * 4;
        if (tc >= num_tokens) break;   // safety; benchmark sizes divide evenly
        int4 v;
        int* vp = (int*)&v;
        int t = tc;
        #pragma unroll
        for (int k = 0; k < 4; ++k) {
            while (t >= next) {        // advances across gaps & empty requests
                ++r;
                next = qsl[r + 1];
                base = nct[idx_mapping[r]] - qsl[r];
            }
            vp[k] = base + t;
            ++t;
        }
        if (tc + 4 <= num_tokens) {
            *(int4*)(pos_out + tc) = v;
        } else {
            for (int k = 0; k < num_tokens - tc; ++k) pos_out[tc + k] = vp[k];
        }
    }
}

extern "C" void kernel_launch(void* const* d_in, const int* in_sizes, int n_in,
                              void* d_out, int out_size, void* d_ws, size_t ws_size,
                              hipStream_t stream) {
    const int* idx_mapping = (const int*)d_in[0];
    const int* qsl         = (const int*)d_in[1];
    const int* nct         = (const int*)d_in[2];
    // d_in[3] (pos buffer) and d_in[4] (seq_lens buffer) are unused inputs.

    int num_reqs     = in_sizes[0];
    int max_num_reqs = in_sizes[2];
    int num_tokens   = in_sizes[3];

    int* out = (int*)d_out;
    int* pos_out = out;
    int* seq_out = out + num_tokens;

    int pos_blocks = (num_tokens + TOK_PER_BLOCK - 1) / TOK_PER_BLOCK;     // 2048
    int seq_blocks = (max_num_reqs + SEQ_PER_BLOCK - 1) / SEQ_PER_BLOCK;   // 16

    dim3 grid(pos_blocks + seq_blocks), block(TPB);
    pos_seq_kernel<<<grid, block, 0, stream>>>(
        idx_mapping, qsl, nct, pos_out, seq_out,
        num_reqs, max_num_reqs, num_tokens, pos_blocks);
}